// Round 8
// baseline (472.113 us; speedup 1.0000x reference)
//
#include <hip/hip_runtime.h>

#define INPUT_DIM 16
#define COLS 273                                   // 1 + 16 + 256
#define ROWS_PER_TILE 16
#define FLOATS_PER_TILE (ROWS_PER_TILE * COLS)     // 4368
#define VEC4_PER_TILE (FLOATS_PER_TILE / 4)        // 1092
#define NBLOCKS 2048                               // 8 resident/CU, persistent

// scales: 1/RRD = 1/d^0.25 = 0.5 ;  1/(sqrt(2)*sqrt(d)) = 1/(4*sqrt(2))
#define S1 0.5f
#define S2 0.17677669529663687f

typedef float f4 __attribute__((ext_vector_type(4)));

// DIAGNOSTIC BUILD: d_out path identical to R7; additionally mirrors each
// output vec4 into d_ws up to 3x (bounds-guarded) to scale the NT-store
// stream to ~1092 MiB so this dispatch surfaces in the rocprof top-5 with
// its own counter row.
__global__ __launch_bounds__(256)
void taylor_exp_kernel(const float* __restrict__ x, float* __restrict__ out,
                       float* __restrict__ ws, size_t wsCap4, int ntiles)
{
    __shared__ float xs[ROWS_PER_TILE * INPUT_DIM];    // 1 KiB input tile
    __shared__ float os[FLOATS_PER_TILE];              // 17472 B output tile

    const int tid = threadIdx.x;
    const int row = tid >> 4;          // 0..15
    const int l   = tid & 15;          // 0..15
    const int base = row * COLS;
    float* o2 = &os[base + 17 + l];
    const f4* xsr = (const f4*)&xs[row * INPUT_DIM];
    const size_t totalVec4 = (size_t)ntiles * VEC4_PER_TILE;
    f4* __restrict__ ws4 = (f4*)ws;

    for (int t = blockIdx.x; t < ntiles; t += NBLOCKS) {
        xs[tid] = x[(long long)t * (ROWS_PER_TILE * INPUT_DIM) + tid];
        __syncthreads();

        // ---- compute phase: branch-free ----
        const float xl = xs[tid];
        const f4 r0 = xsr[0], r1 = xsr[1], r2 = xsr[2], r3 = xsr[3];

        os[base + 1 + l] = xl * S1;
        if (l == 0) os[base] = 1.0f;

        o2[ 0 * 16] = (r0[0] * xl) * S2;
        o2[ 1 * 16] = (r0[1] * xl) * S2;
        o2[ 2 * 16] = (r0[2] * xl) * S2;
        o2[ 3 * 16] = (r0[3] * xl) * S2;
        o2[ 4 * 16] = (r1[0] * xl) * S2;
        o2[ 5 * 16] = (r1[1] * xl) * S2;
        o2[ 6 * 16] = (r1[2] * xl) * S2;
        o2[ 7 * 16] = (r1[3] * xl) * S2;
        o2[ 8 * 16] = (r2[0] * xl) * S2;
        o2[ 9 * 16] = (r2[1] * xl) * S2;
        o2[10 * 16] = (r2[2] * xl) * S2;
        o2[11 * 16] = (r2[3] * xl) * S2;
        o2[12 * 16] = (r3[0] * xl) * S2;
        o2[13 * 16] = (r3[1] * xl) * S2;
        o2[14 * 16] = (r3[2] * xl) * S2;
        o2[15 * 16] = (r3[3] * xl) * S2;

        __syncthreads();

        // ---- copy phase: LDS -> global NT stores, + 3x mirror into d_ws ----
        f4* __restrict__ out4 = (f4*)(out + (long long)t * FLOATS_PER_TILE);
        const f4* os4 = (const f4*)os;
        const size_t gvBase = (size_t)t * VEC4_PER_TILE;

        #pragma unroll
        for (int it = 0; it < 5; ++it) {
            const int v = tid + it * 256;        // 1092 = 4*256 + 68
            if (v < VEC4_PER_TILE) {
                const f4 val = os4[v];
                __builtin_nontemporal_store(val, &out4[v]);
                const size_t gv = gvBase + v;
                #pragma unroll
                for (int r = 0; r < 3; ++r) {
                    const size_t wi = gv + (size_t)r * totalVec4;
                    if (wi < wsCap4) {
                        __builtin_nontemporal_store(val, &ws4[wi]);
                    }
                }
            }
        }
        __syncthreads();
    }
}

extern "C" void kernel_launch(void* const* d_in, const int* in_sizes, int n_in,
                              void* d_out, int out_size, void* d_ws, size_t ws_size,
                              hipStream_t stream)
{
    const float* x = (const float*)d_in[0];
    float* out = (float*)d_out;

    const int nrows  = in_sizes[0] / INPUT_DIM;        // 262144
    const int ntiles = nrows / ROWS_PER_TILE;          // 16384
    const size_t wsCap4 = ws_size / 16;                // f4 slots in d_ws

    taylor_exp_kernel<<<NBLOCKS, 256, 0, stream>>>(x, out, (float*)d_ws, wsCap4, ntiles);
}

// Round 9
// 299.290 us; speedup vs baseline: 1.5774x; 1.5774x over previous
//
#include <hip/hip_runtime.h>

#define INPUT_DIM 16
#define COLS 273                                   // 1 + 16 + 256
#define ROWS_PER_TILE 16
#define TILE_IN_FLOATS 256                         // 16 rows x 16 cols
#define FLOATS_PER_TILE (ROWS_PER_TILE * COLS)     // 4368
#define VEC4_PER_TILE (FLOATS_PER_TILE / 4)        // 1092
#define NBLOCKS 2048                               // 8 resident/CU, persistent

// scales: 1/RRD = 1/d^0.25 = 0.5 ;  1/(sqrt(2)*sqrt(d)) = 1/(4*sqrt(2))
#define S1 0.5f
#define S2 0.17677669529663687f

typedef float f4 __attribute__((ext_vector_type(4)));
typedef const __attribute__((address_space(1))) unsigned int* gas_ptr;
typedef __attribute__((address_space(3))) unsigned int* las_ptr;

// LDS-only barrier: drain LDS ops but leave global stores in flight
// (plain __syncthreads() emits s_waitcnt vmcnt(0) -> store-pipe drain, the limiter)
#define LGKM_BARRIER() do {                                   \
    asm volatile("s_waitcnt lgkmcnt(0)" ::: "memory");        \
    __builtin_amdgcn_s_barrier();                             \
} while (0)

__global__ __launch_bounds__(256)
void taylor_exp_kernel(const float* __restrict__ x, float* __restrict__ out, int ntiles)
{
    __shared__ float xs[2][TILE_IN_FLOATS];            // double-buffered input tile
    __shared__ float os[FLOATS_PER_TILE];              // output tile

    const int tid  = threadIdx.x;
    const int wave = tid >> 6;
    const int row  = tid >> 4;         // 0..15
    const int l    = tid & 15;         // 0..15
    const int base = row * COLS;
    float* o2 = &os[base + 17 + l];

    const int t0    = blockIdx.x;
    const int tiles = ntiles / NBLOCKS;                // 8

    // async stage of tile t into xs[buf]: per-lane global src, wave-uniform
    // LDS base + lane*4 implicit (width=4)
    #define GLL(t, buf) do {                                                      \
        const float* gp_ = x + (size_t)(t) * TILE_IN_FLOATS + tid;                \
        __builtin_amdgcn_global_load_lds((gas_ptr)(const void*)gp_,               \
                                         (las_ptr)(void*)&xs[buf][wave << 6],     \
                                         4, 0, 0);                                \
    } while (0)

    // prologue: stage tile 0, full drain once
    GLL(t0, 0);
    asm volatile("s_waitcnt vmcnt(0)" ::: "memory");
    __builtin_amdgcn_s_barrier();

    int p = 0;
    #pragma unroll 1
    for (int k = 0; k < tiles; ++k) {
        const int t = t0 + k * NBLOCKS;

        // ---- compute phase: read xs[p], build os (branch-free) ----
        const float xl = xs[p][tid];
        const f4* xsr = (const f4*)&xs[p][row * INPUT_DIM];
        const f4 r0 = xsr[0], r1 = xsr[1], r2 = xsr[2], r3 = xsr[3];

        os[base + 1 + l] = xl * S1;
        if (l == 0) os[base] = 1.0f;

        // os[base + 17 + j*16 + l] = (x[j]*x[l])*S2  (rounding order: absmax==0)
        o2[ 0 * 16] = (r0[0] * xl) * S2;
        o2[ 1 * 16] = (r0[1] * xl) * S2;
        o2[ 2 * 16] = (r0[2] * xl) * S2;
        o2[ 3 * 16] = (r0[3] * xl) * S2;
        o2[ 4 * 16] = (r1[0] * xl) * S2;
        o2[ 5 * 16] = (r1[1] * xl) * S2;
        o2[ 6 * 16] = (r1[2] * xl) * S2;
        o2[ 7 * 16] = (r1[3] * xl) * S2;
        o2[ 8 * 16] = (r2[0] * xl) * S2;
        o2[ 9 * 16] = (r2[1] * xl) * S2;
        o2[10 * 16] = (r2[2] * xl) * S2;
        o2[11 * 16] = (r2[3] * xl) * S2;
        o2[12 * 16] = (r3[0] * xl) * S2;
        o2[13 * 16] = (r3[1] * xl) * S2;
        o2[14 * 16] = (r3[2] * xl) * S2;
        o2[15 * 16] = (r3[3] * xl) * S2;

        // prefetch next tile into the other buffer BEFORE this tile's stores,
        // so its completion can be awaited with a counted vmcnt
        if (k + 1 < tiles) GLL(t0 + (k + 1) * NBLOCKS, p ^ 1);

        LGKM_BARRIER();       // os complete; xs[p] reads drained; stores still fly

        // ---- copy phase: LDS -> global NT streaming stores ----
        // exactly 5 stores per wave (tail clamped -> benign duplicate of the
        // last vec4) so per-wave in-flight store count is uniform
        const f4* os4 = (const f4*)os;
        f4* __restrict__ out4 = (f4*)(out + (size_t)t * FLOATS_PER_TILE);
        #pragma unroll
        for (int it = 0; it < 5; ++it) {
            int v = tid + it * 256;                       // 1092 = 4*256 + 68
            v = v < VEC4_PER_TILE ? v : (VEC4_PER_TILE - 1);
            __builtin_nontemporal_store(os4[v], &out4[v]);
        }

        // counted wait: per wave, newest 5 vmem ops are this tile's stores;
        // everything older (the prefetch gll + previous tile's stores) done.
        asm volatile("s_waitcnt vmcnt(5) lgkmcnt(0)" ::: "memory");
        __builtin_amdgcn_s_barrier();     // xs[p^1] now valid for all waves
        p ^= 1;
    }
    #undef GLL
}

extern "C" void kernel_launch(void* const* d_in, const int* in_sizes, int n_in,
                              void* d_out, int out_size, void* d_ws, size_t ws_size,
                              hipStream_t stream)
{
    const float* x = (const float*)d_in[0];
    float* out = (float*)d_out;

    const int nrows  = in_sizes[0] / INPUT_DIM;        // 262144
    const int ntiles = nrows / ROWS_PER_TILE;          // 16384

    taylor_exp_kernel<<<NBLOCKS, 256, 0, stream>>>(x, out, ntiles);
}

// Round 10
// 297.116 us; speedup vs baseline: 1.5890x; 1.0073x over previous
//
#include <hip/hip_runtime.h>

#define INPUT_DIM 16
#define COLS 273                                   // 1 + 16 + 256
#define ROWS_PER_TILE 16
#define TILE_IN_FLOATS 256                         // 16 rows x 16 cols
#define FLOATS_PER_TILE (ROWS_PER_TILE * COLS)     // 4368
#define VEC4_PER_TILE (FLOATS_PER_TILE / 4)        // 1092
#define NBLOCKS 2048                               // persistent
#define TILES_PER_BLOCK 8                          // 16384 tiles total

// scales: 1/RRD = 1/d^0.25 = 0.5 ;  1/(sqrt(2)*sqrt(d)) = 1/(4*sqrt(2))
#define S1 0.5f
#define S2 0.17677669529663687f

typedef float f4 __attribute__((ext_vector_type(4)));
typedef const __attribute__((address_space(1))) unsigned int* gas_ptr;
typedef __attribute__((address_space(3))) unsigned int* las_ptr;

// LDS-only barrier: drain LDS ops, leave global stores in flight
#define LGKM_BARRIER() do {                                   \
    asm volatile("s_waitcnt lgkmcnt(0)" ::: "memory");        \
    __builtin_amdgcn_s_barrier();                             \
} while (0)

__global__ __launch_bounds__(256)
void taylor_exp_kernel(const float* __restrict__ x, float* __restrict__ out, int ntiles)
{
    __shared__ float xs[TILES_PER_BLOCK][TILE_IN_FLOATS];  // 8 KiB: ALL input up front
    __shared__ float os[FLOATS_PER_TILE];                  // 17472 B output tile

    const int tid  = threadIdx.x;
    const int wave = tid >> 6;
    const int row  = tid >> 4;         // 0..15
    const int l    = tid & 15;         // 0..15
    const int base = row * COLS;
    float* o2 = &os[base + 17 + l];

    // block owns tiles [bid*8, bid*8+8): contiguous 8 KiB in, 140 KiB out
    const size_t tileBase = (size_t)blockIdx.x * TILES_PER_BLOCK;

    // ---- prologue: hoist ALL input reads (async global->LDS), one drain ----
    {
        const float* gbase = x + tileBase * TILE_IN_FLOATS + tid;
        #pragma unroll
        for (int k = 0; k < TILES_PER_BLOCK; ++k) {
            __builtin_amdgcn_global_load_lds(
                (gas_ptr)(const void*)(gbase + k * TILE_IN_FLOATS),
                (las_ptr)(void*)&xs[k][wave << 6], 4, 0, 0);
        }
        asm volatile("s_waitcnt vmcnt(0)" ::: "memory");
        __builtin_amdgcn_s_barrier();
    }

    // ---- main loop: ZERO vmem reads; pure NT write stream ----
    #pragma unroll 1
    for (int k = 0; k < TILES_PER_BLOCK; ++k) {
        const size_t t = tileBase + k;
        if (t >= (size_t)ntiles) break;

        // compute phase: read xs[k], build os (branch-free)
        const float xl = xs[k][tid];
        const f4* xsr = (const f4*)&xs[k][row * INPUT_DIM];
        const f4 r0 = xsr[0], r1 = xsr[1], r2 = xsr[2], r3 = xsr[3];

        os[base + 1 + l] = xl * S1;
        if (l == 0) os[base] = 1.0f;

        // os[base + 17 + j*16 + l] = (x[j]*x[l])*S2  (rounding order: absmax==0)
        o2[ 0 * 16] = (r0[0] * xl) * S2;
        o2[ 1 * 16] = (r0[1] * xl) * S2;
        o2[ 2 * 16] = (r0[2] * xl) * S2;
        o2[ 3 * 16] = (r0[3] * xl) * S2;
        o2[ 4 * 16] = (r1[0] * xl) * S2;
        o2[ 5 * 16] = (r1[1] * xl) * S2;
        o2[ 6 * 16] = (r1[2] * xl) * S2;
        o2[ 7 * 16] = (r1[3] * xl) * S2;
        o2[ 8 * 16] = (r2[0] * xl) * S2;
        o2[ 9 * 16] = (r2[1] * xl) * S2;
        o2[10 * 16] = (r2[2] * xl) * S2;
        o2[11 * 16] = (r2[3] * xl) * S2;
        o2[12 * 16] = (r3[0] * xl) * S2;
        o2[13 * 16] = (r3[1] * xl) * S2;
        o2[14 * 16] = (r3[2] * xl) * S2;
        o2[15 * 16] = (r3[3] * xl) * S2;

        LGKM_BARRIER();   // os complete; stores from prior rounds still in flight

        // copy phase: LDS -> global NT streaming stores (no waits here)
        const f4* os4 = (const f4*)os;
        f4* __restrict__ out4 = (f4*)(out + t * FLOATS_PER_TILE);
        #pragma unroll
        for (int it = 0; it < 5; ++it) {
            const int v = tid + it * 256;                 // 1092 = 4*256 + 68
            if (v < VEC4_PER_TILE) {
                __builtin_nontemporal_store(os4[v], &out4[v]);
            }
        }

        LGKM_BARRIER();   // store-phase ds_reads drained -> os reusable next round
    }
    // implicit vmcnt(0) store drain at s_endpgm
}

extern "C" void kernel_launch(void* const* d_in, const int* in_sizes, int n_in,
                              void* d_out, int out_size, void* d_ws, size_t ws_size,
                              hipStream_t stream)
{
    const float* x = (const float*)d_in[0];
    float* out = (float*)d_out;

    const int nrows  = in_sizes[0] / INPUT_DIM;        // 262144
    const int ntiles = nrows / ROWS_PER_TILE;          // 16384

    taylor_exp_kernel<<<NBLOCKS, 256, 0, stream>>>(x, out, ntiles);
}